// Round 6
// baseline (125.160 us; speedup 1.0000x reference)
//
#include <hip/hip_runtime.h>

#define D 64
#define ITEM_PAD 100000
#define NROWS_I (ITEM_PAD + 1)
#define LSEQ 200
#define BATCH 4096
#define NEG_W 0.1f
#define NBI 512                         // gram_item partial blocks
#define NBU 64                          // gram_user partial blocks
#define GSZ (D * D)                     // 4096

// ws layout (floats):
#define TAB_FLOATS 1600064              // fp8 table: 100001 rows x 64 fp8 (6.4 MB)
#define PITEM_OFF  ((size_t)TAB_FLOATS)
#define PUSER_OFF  (PITEM_OFF + (size_t)NBI * GSZ)
#define POS_OFF    (PUSER_OFF + (size_t)NBU * GSZ)
#define WS3_OFF    (POS_OFF + BATCH)
#define CTR_OFF    (WS3_OFF + 256)

// decode 4 fp8 (one packed uint) -> 4 floats
__device__ __forceinline__ void fp8x4_dec(unsigned w, float* o) {
    auto lo = __builtin_amdgcn_cvt_pk_f32_fp8((int)w, false);
    auto hi = __builtin_amdgcn_cvt_pk_f32_fp8((int)w, true);
    o[0] = lo[0]; o[1] = lo[1]; o[2] = hi[0]; o[3] = hi[1];
}

// ---------------------------------------------------------------------------
// K1: item_W fp32 -> fp8 e4m3 table (value*8, descale folded downstream).
// Each thread converts 8 floats -> uint2. Also zero-inits the K3 counter.
// ---------------------------------------------------------------------------
__global__ void convert_fp8(const float* __restrict__ item_W,
                            float* __restrict__ ws) {
    if (blockIdx.x == 0 && threadIdx.x == 0)
        ((unsigned*)(ws + CTR_OFF))[0] = 0u;
    unsigned* __restrict__ tab = (unsigned*)ws;
    const long long n8 = (long long)NROWS_I * 8;   // 800008 uint2 units
    const long long stride = (long long)gridDim.x * 256;
    for (long long i = (long long)blockIdx.x * 256 + threadIdx.x; i < n8; i += stride) {
        const float4 a = *(const float4*)(item_W + i * 8);
        const float4 b = *(const float4*)(item_W + i * 8 + 4);
        int lo = 0, hi = 0;
        lo = __builtin_amdgcn_cvt_pk_fp8_f32(a.x * 8.f, a.y * 8.f, lo, false);
        lo = __builtin_amdgcn_cvt_pk_fp8_f32(a.z * 8.f, a.w * 8.f, lo, true);
        hi = __builtin_amdgcn_cvt_pk_fp8_f32(b.x * 8.f, b.y * 8.f, hi, false);
        hi = __builtin_amdgcn_cvt_pk_fp8_f32(b.z * 8.f, b.w * 8.f, hi, true);
        uint2 v; v.x = (unsigned)lo; v.y = (unsigned)hi;
        *(uint2*)(tab + i * 2) = v;
    }
}

// ---------------------------------------------------------------------------
// K2: gram partials + pos-loss partials, concurrent in one launch.
//   blocks [0, NBI)          : item-Gram partial from fp8 table (x0.125 decode)
//   blocks [NBI, NBI+NBU)    : user-Gram partial (fp32 gather via uids)
//   blocks [NBI+NBU, +BATCH) : pos-loss row partial from fp8 table
// ---------------------------------------------------------------------------
__global__ void gram_pos(const int* __restrict__ uids,
                         const int* __restrict__ pos_iids,
                         const float* __restrict__ user_W,
                         const float* __restrict__ h,
                         float* __restrict__ ws) {
    __shared__ float smem[32 * D];   // 8 KB
    const int bid  = blockIdx.x;
    const int t    = threadIdx.x;
    const int lane = t & 63;
    const int wave = t >> 6;

    if (bid < NBI + NBU) {
        const bool item = (bid < NBI);
        const int nrows  = item ? NROWS_I : BATCH;
        const int stride = item ? NBI : NBU;
        const int b0     = item ? bid : bid - NBI;
        float* __restrict__ out =
            ws + (item ? PITEM_OFF + (size_t)b0 * GSZ : PUSER_OFF + (size_t)b0 * GSZ);
        const unsigned* __restrict__ tab = (const unsigned*)ws;

        const int ti = t >> 4, tj = t & 15;      // compute mapping (4x4 tile)
        const int si = t >> 3, sj = t & 7;       // item staging: 32 rows x 8 uint2
        float acc[4][4] = {{0.f,0.f,0.f,0.f},{0.f,0.f,0.f,0.f},
                           {0.f,0.f,0.f,0.f},{0.f,0.f,0.f,0.f}};
        const int nchunks = (nrows + 31) >> 5;

        // prefetch first chunk
        uint2  pi = make_uint2(0u, 0u);
        float4 va = make_float4(0.f,0.f,0.f,0.f), vb = va;
        int c = b0;
        if (c < nchunks) {
            if (item) {
                const int r = (c << 5) + si;
                if (r < nrows) pi = *(const uint2*)(tab + ((size_t)r * 8 + sj) * 2);
            } else {
                const int ra = (c << 5) + ti, rb = ra + 16;
                if (ra < nrows) va = *(const float4*)(user_W + (size_t)uids[ra] * D + tj * 4);
                if (rb < nrows) vb = *(const float4*)(user_W + (size_t)uids[rb] * D + tj * 4);
            }
        }

        while (c < nchunks) {
            __syncthreads();
            if (item) {
                float f[8];
                fp8x4_dec(pi.x, f);
                fp8x4_dec(pi.y, f + 4);
                float4 o0 = make_float4(f[0]*0.125f, f[1]*0.125f, f[2]*0.125f, f[3]*0.125f);
                float4 o1 = make_float4(f[4]*0.125f, f[5]*0.125f, f[6]*0.125f, f[7]*0.125f);
                *(float4*)(smem + si * D + sj * 8)     = o0;
                *(float4*)(smem + si * D + sj * 8 + 4) = o1;
            } else {
                *(float4*)(smem + ti * D + tj * 4)        = va;
                *(float4*)(smem + (ti + 16) * D + tj * 4) = vb;
            }
            __syncthreads();

            const int cn = c + stride;
            pi = make_uint2(0u, 0u);
            va = make_float4(0.f,0.f,0.f,0.f); vb = va;
            if (cn < nchunks) {
                if (item) {
                    const int r = (cn << 5) + si;
                    if (r < nrows) pi = *(const uint2*)(tab + ((size_t)r * 8 + sj) * 2);
                } else {
                    const int ra = (cn << 5) + ti, rb = ra + 16;
                    if (ra < nrows) va = *(const float4*)(user_W + (size_t)uids[ra] * D + tj * 4);
                    if (rb < nrows) vb = *(const float4*)(user_W + (size_t)uids[rb] * D + tj * 4);
                }
            }

            #pragma unroll
            for (int r2 = 0; r2 < 32; ++r2) {
                float xi[4], xj[4];
                *(float4*)xi = *(const float4*)(smem + r2 * D + ti * 4);
                *(float4*)xj = *(const float4*)(smem + r2 * D + tj * 4);
                #pragma unroll
                for (int a = 0; a < 4; ++a)
                    #pragma unroll
                    for (int b2 = 0; b2 < 4; ++b2)
                        acc[a][b2] += xi[a] * xj[b2];
            }
            c = cn;
        }
        #pragma unroll
        for (int a = 0; a < 4; ++a)
            *(float4*)(out + (ti * 4 + a) * D + tj * 4) = *(const float4*)acc[a];
    } else {
        // ---- pos-loss partial from fp8 table ----
        __shared__ float uh[D];
        __shared__ int   sidx[LSEQ];
        __shared__ float red[4];
        const int b = bid - (NBI + NBU);
        const uint2* __restrict__ tab = (const uint2*)ws;

        if (t < LSEQ) sidx[t] = pos_iids[(size_t)b * LSEQ + t];
        if (t >= 192) {
            const int j = t - 192;
            uh[j] = user_W[(size_t)uids[b] * D + j] * h[j] * 0.125f;  // descale
        }
        __syncthreads();

        const int p    = lane >> 3;      // 0..7 (row slot in wave)
        const int q    = lane & 7;       // 0..7 (8 d's per lane)
        const int base = wave * 8 + p;   // 0..31

        float u8[8];
        *(float4*)(u8 + 0) = *(const float4*)(uh + q * 8);
        *(float4*)(u8 + 4) = *(const float4*)(uh + q * 8 + 4);

        int ids[7];
        #pragma unroll
        for (int k = 0; k < 7; ++k) {
            const int l = base + 32 * k;
            ids[k] = (l < LSEQ) ? sidx[l] : ITEM_PAD;
        }
        uint2 rows[7];
        #pragma unroll
        for (int k = 0; k < 7; ++k) {
            uint2 v = make_uint2(0u, 0u);
            if (ids[k] != ITEM_PAD)
                v = tab[(size_t)ids[k] * 8 + q];
            rows[k] = v;
        }

        float local = 0.f;
        #pragma unroll
        for (int k = 0; k < 7; ++k) {
            float f[8];
            fp8x4_dec(rows[k].x, f);
            fp8x4_dec(rows[k].y, f + 4);
            float s = f[0]*u8[0] + f[1]*u8[1] + f[2]*u8[2] + f[3]*u8[3]
                    + f[4]*u8[4] + f[5]*u8[5] + f[6]*u8[6] + f[7]*u8[7];
            s += __shfl_xor(s, 1);
            s += __shfl_xor(s, 2);
            s += __shfl_xor(s, 4);
            if (q == 0)
                local += (1.0f - NEG_W) * s * s - 2.0f * s;   // s==0 for masked/oob
        }
        local += __shfl_xor(local, 1);
        local += __shfl_xor(local, 2);
        local += __shfl_xor(local, 4);
        local += __shfl_xor(local, 8);
        local += __shfl_xor(local, 16);
        local += __shfl_xor(local, 32);
        if (lane == 0) red[wave] = local;
        __syncthreads();
        if (t == 0)
            ws[POS_OFF + b] = red[0] + red[1] + red[2] + red[3];
    }
}

// ---------------------------------------------------------------------------
// K3: 256 blocks. Block bb: Gi/Gu reduce for k-slice [bb*16,+16), apply
// NEG_W*h_i*h_j, add pos[bb*16+t] slice -> ws3[bb]. Last block (device-scope
// counter + fences) sums ws3 -> out[0].
// ---------------------------------------------------------------------------
__global__ void reduce_final(const float* __restrict__ ws,
                             const float* __restrict__ h,
                             float* __restrict__ ws3,
                             unsigned* __restrict__ counter,
                             float* __restrict__ out) {
    __shared__ float rI[4][16];
    __shared__ float rU[4][16];
    __shared__ int isLast;
    const int bb = blockIdx.x;
    const int t  = threadIdx.x;
    const int kk = t & 15;
    const int ps = t >> 4;        // 0..15
    const int lane = t & 63;
    const int wave = t >> 6;
    const int k  = bb * 16 + kk;

    float si = 0.f, su = 0.f;
    #pragma unroll 8
    for (int p = ps; p < NBI; p += 16) si += ws[PITEM_OFF + (size_t)p * GSZ + k];
    #pragma unroll
    for (int p = ps; p < NBU; p += 16) su += ws[PUSER_OFF + (size_t)p * GSZ + k];

    si += __shfl_xor(si, 16); si += __shfl_xor(si, 32);
    su += __shfl_xor(su, 16); su += __shfl_xor(su, 32);
    if (lane < 16) { rI[wave][kk] = si; rU[wave][kk] = su; }
    __syncthreads();

    if (wave == 0) {
        float c = 0.f;
        if (t < 16) {
            const float Gi = rI[0][t] + rI[1][t] + rI[2][t] + rI[3][t];
            const float Gu = rU[0][t] + rU[1][t] + rU[2][t] + rU[3][t];
            const int kg = bb * 16 + t;
            const int i = kg >> 6, j = kg & 63;
            c = NEG_W * Gi * Gu * h[i] * h[j] + ws[POS_OFF + bb * 16 + t];
        }
        c += __shfl_xor(c, 1);
        c += __shfl_xor(c, 2);
        c += __shfl_xor(c, 4);
        c += __shfl_xor(c, 8);
        if (lane == 0) ws3[bb] = c;
    }

    if (t == 0) {
        __threadfence();
        isLast = (atomicAdd(counter, 1u) == 255u);
    }
    __syncthreads();
    if (isLast) {
        __threadfence();
        float s = ws3[t];
        s += __shfl_xor(s, 1);
        s += __shfl_xor(s, 2);
        s += __shfl_xor(s, 4);
        s += __shfl_xor(s, 8);
        s += __shfl_xor(s, 16);
        s += __shfl_xor(s, 32);
        __shared__ float red[4];
        if (lane == 0) red[wave] = s;
        __syncthreads();
        if (t == 0) out[0] = red[0] + red[1] + red[2] + red[3];
    }
}

extern "C" void kernel_launch(void* const* d_in, const int* in_sizes, int n_in,
                              void* d_out, int out_size, void* d_ws, size_t ws_size,
                              hipStream_t stream) {
    const int*   uids     = (const int*)d_in[0];
    const int*   pos_iids = (const int*)d_in[1];
    const float* user_W   = (const float*)d_in[2];
    const float* item_W   = (const float*)d_in[3];
    const float* h        = (const float*)d_in[4];
    float* out = (float*)d_out;
    float* ws  = (float*)d_ws;

    convert_fp8<<<1024, 256, 0, stream>>>(item_W, ws);
    gram_pos<<<NBI + NBU + BATCH, 256, 0, stream>>>(uids, pos_iids, user_W, h, ws);
    reduce_final<<<256, 256, 0, stream>>>(ws, h, ws + WS3_OFF,
                                          (unsigned*)(ws + CTR_OFF), out);
}